// Round 3
// baseline (839.628 us; speedup 1.0000x reference)
//
#include <hip/hip_runtime.h>
#include <math.h>

#define NDIM 512
#define NLAYERS 8
#define NPATCH 32
#define NHEADS 8
#define NDH 64
#define KWIN 127
#define SEQ 512
#define QKVD 1536
#define FFD 2048

enum { EP_NONE = 0, EP_BIAS = 1, EP_BIAS_GELU = 3 };

typedef __attribute__((ext_vector_type(4))) float f32x4;
typedef __attribute__((ext_vector_type(8))) short bf16x8;

__device__ __forceinline__ float gelu_exact(float v) {
  return 0.5f * v * (1.0f + erff(v * 0.70710678118654752f));
}

__device__ __forceinline__ short f2bf(float f) {
  unsigned u = __float_as_uint(f);
  u = u + 0x7fffu + ((u >> 16) & 1u);   // RNE
  return (short)(u >> 16);
}

// ---------------------------------------------------------------------------
// bf16 MFMA GEMM: C[m][n] = epi(sum_k A[m][k]*W[n][k]), A fp32 [M][K],
// W fp32 [N][K]. fp32->bf16 conversion fused into LDS staging.
// 64x64 tile, 256 thr (4 waves, each a 32x32 quadrant of 2x2 16x16 frags).
// gridDim.z = split-K slices; EP_NONE writes fp32 partials at out + z*M*N.
// ---------------------------------------------------------------------------
template <int EP>
__global__ __launch_bounds__(256) void gemm_bf16(
    const float* __restrict__ A, const float* __restrict__ W,
    const float* __restrict__ bias, float* __restrict__ out,
    int M, int N, int K)
{
  // 40-short row stride = 80B: 16B-aligned for b128, <=2-way bank alias (free)
  __shared__ short As[64][40];
  __shared__ short Bs[64][40];

  const int tid = threadIdx.x;
  const int wid = tid >> 6;
  const int lane = tid & 63;
  const int bm = blockIdx.y * 64;
  const int bn = blockIdx.x * 64;
  const int wr = (wid >> 1) * 32;   // wave quadrant M offset
  const int wc = (wid & 1) * 32;    // wave quadrant N offset
  const int lr = lane & 15;         // fragment row/col index
  const int lkg = lane >> 4;        // k-group 0..3

  const int sr = tid >> 2;          // staging row 0..63
  const int sc = (tid & 3) * 8;     // staging col 0,8,16,24

  const int kchunk = K / gridDim.z;
  const int kbeg = blockIdx.z * kchunk;
  const int kend = kbeg + kchunk;

  f32x4 acc[2][2] = {};

  const float* aptr = &A[(size_t)(bm + sr) * K + sc];
  const float* bptr = &W[(size_t)(bn + sr) * K + sc];

  // prefetch first tile into registers
  float4 a0 = *(const float4*)&aptr[kbeg];
  float4 a1 = *(const float4*)&aptr[kbeg + 4];
  float4 b0 = *(const float4*)&bptr[kbeg];
  float4 b1 = *(const float4*)&bptr[kbeg + 4];

  for (int k0 = kbeg; k0 < kend; k0 += 32) {
    __syncthreads();  // previous iteration's LDS reads done
    {
      bf16x8 av, bv;
      av[0] = f2bf(a0.x); av[1] = f2bf(a0.y); av[2] = f2bf(a0.z); av[3] = f2bf(a0.w);
      av[4] = f2bf(a1.x); av[5] = f2bf(a1.y); av[6] = f2bf(a1.z); av[7] = f2bf(a1.w);
      bv[0] = f2bf(b0.x); bv[1] = f2bf(b0.y); bv[2] = f2bf(b0.z); bv[3] = f2bf(b0.w);
      bv[4] = f2bf(b1.x); bv[5] = f2bf(b1.y); bv[6] = f2bf(b1.z); bv[7] = f2bf(b1.w);
      *(bf16x8*)&As[sr][sc] = av;
      *(bf16x8*)&Bs[sr][sc] = bv;
    }
    __syncthreads();

    // issue next-tile global loads before compute (hide HBM latency)
    if (k0 + 32 < kend) {
      a0 = *(const float4*)&aptr[k0 + 32];
      a1 = *(const float4*)&aptr[k0 + 36];
      b0 = *(const float4*)&bptr[k0 + 32];
      b1 = *(const float4*)&bptr[k0 + 36];
    }

    bf16x8 af[2], bfr[2];
#pragma unroll
    for (int f = 0; f < 2; ++f) {
      af[f]  = *(const bf16x8*)&As[wr + f * 16 + lr][lkg * 8];
      bfr[f] = *(const bf16x8*)&Bs[wc + f * 16 + lr][lkg * 8];
    }
#pragma unroll
    for (int fm = 0; fm < 2; ++fm)
#pragma unroll
      for (int fn = 0; fn < 2; ++fn)
        acc[fm][fn] = __builtin_amdgcn_mfma_f32_16x16x32_bf16(
            af[fm], bfr[fn], acc[fm][fn], 0, 0, 0);
  }

  float* o = out + (EP == EP_NONE ? (size_t)blockIdx.z * M * N : (size_t)0);
#pragma unroll
  for (int fm = 0; fm < 2; ++fm) {
#pragma unroll
    for (int fn = 0; fn < 2; ++fn) {
      const int n = bn + wc + fn * 16 + lr;
#pragma unroll
      for (int j = 0; j < 4; ++j) {
        const int m = bm + wr + fm * 16 + lkg * 4 + j;
        float v = acc[fm][fn][j];
        if (EP != EP_NONE) v += bias[n];
        if (EP == EP_BIAS_GELU) v = gelu_exact(v);
        o[(size_t)m * N + n] = v;
      }
    }
  }
}

// ---------------------------------------------------------------------------
// fp32 fallback GEMM (tiny patch embed, K=32)
// ---------------------------------------------------------------------------
template <int EP>
__global__ __launch_bounds__(256) void gemm_nt(
    const float* __restrict__ A, const float* __restrict__ W,
    const float* __restrict__ bias, float* __restrict__ out,
    int M, int N, int K)
{
  __shared__ float As[16][68];
  __shared__ float Bs[16][68];
  const int tid = threadIdx.x;
  const int tx = tid & 15;
  const int ty = tid >> 4;
  const int bm = blockIdx.y * 64;
  const int bn = blockIdx.x * 64;
  const int sr = tid >> 2;
  const int sk = (tid & 3) << 2;

  float acc[4][4] = {};

  for (int k0 = 0; k0 < K; k0 += 16) {
    const float4 av = *(const float4*)&A[(size_t)(bm + sr) * K + k0 + sk];
    const float4 bv = *(const float4*)&W[(size_t)(bn + sr) * K + k0 + sk];
    __syncthreads();
    As[sk + 0][sr] = av.x; As[sk + 1][sr] = av.y; As[sk + 2][sr] = av.z; As[sk + 3][sr] = av.w;
    Bs[sk + 0][sr] = bv.x; Bs[sk + 1][sr] = bv.y; Bs[sk + 2][sr] = bv.z; Bs[sk + 3][sr] = bv.w;
    __syncthreads();
#pragma unroll
    for (int kk = 0; kk < 16; ++kk) {
      const float4 a = *(const float4*)&As[kk][ty << 2];
      const float4 b = *(const float4*)&Bs[kk][tx << 2];
      const float av4[4] = {a.x, a.y, a.z, a.w};
      const float bv4[4] = {b.x, b.y, b.z, b.w};
#pragma unroll
      for (int i = 0; i < 4; ++i)
#pragma unroll
        for (int j = 0; j < 4; ++j)
          acc[i][j] = fmaf(av4[i], bv4[j], acc[i][j]);
    }
  }

#pragma unroll
  for (int i = 0; i < 4; ++i) {
    const int m = bm + (ty << 2) + i;
#pragma unroll
    for (int j = 0; j < 4; ++j) {
      const int n = bn + (tx << 2) + j;
      float v = acc[i][j];
      if (EP != EP_NONE) v += bias[n];
      if (EP == EP_BIAS_GELU) v = gelu_exact(v);
      out[(size_t)m * N + n] = v;
    }
  }
}

// ---------------------------------------------------------------------------
// fused split-K reduce + residual + (optional) LayerNorm.
// one wave per row: h[row] = h[row] + bias + sum_{s<4} tmp[s][row];
// if DO_LN, lnout[row] = LN(h[row]) with g/b.
// ---------------------------------------------------------------------------
template <bool DO_LN>
__global__ __launch_bounds__(64) void reduce_ln(
    const float* __restrict__ tmp, const float* __restrict__ bias,
    float* __restrict__ h, const float* __restrict__ g,
    const float* __restrict__ b, float* __restrict__ lnout)
{
  const int row = blockIdx.x;
  const int lane = threadIdx.x;
  const int col = lane * 8;
  const size_t base = (size_t)row * NDIM + col;

  float v[8];
  {
    const float4 r0 = *(const float4*)&h[base];
    const float4 r1 = *(const float4*)&h[base + 4];
    const float4 c0 = *(const float4*)&bias[col];
    const float4 c1 = *(const float4*)&bias[col + 4];
    v[0] = r0.x + c0.x; v[1] = r0.y + c0.y; v[2] = r0.z + c0.z; v[3] = r0.w + c0.w;
    v[4] = r1.x + c1.x; v[5] = r1.y + c1.y; v[6] = r1.z + c1.z; v[7] = r1.w + c1.w;
  }
#pragma unroll
  for (int s = 0; s < 4; ++s) {
    const float4 t0 = *(const float4*)&tmp[(size_t)s * (SEQ * NDIM) + base];
    const float4 t1 = *(const float4*)&tmp[(size_t)s * (SEQ * NDIM) + base + 4];
    v[0] += t0.x; v[1] += t0.y; v[2] += t0.z; v[3] += t0.w;
    v[4] += t1.x; v[5] += t1.y; v[6] += t1.z; v[7] += t1.w;
  }

  *(float4*)&h[base]     = make_float4(v[0], v[1], v[2], v[3]);
  *(float4*)&h[base + 4] = make_float4(v[4], v[5], v[6], v[7]);

  if (DO_LN) {
    float s = 0.0f, sq = 0.0f;
#pragma unroll
    for (int i = 0; i < 8; ++i) { s += v[i]; sq += v[i] * v[i]; }
#pragma unroll
    for (int m = 1; m < 64; m <<= 1) {
      s  += __shfl_xor(s, m);
      sq += __shfl_xor(sq, m);
    }
    const float mean = s * (1.0f / NDIM);
    const float inv = 1.0f / sqrtf(sq * (1.0f / NDIM) - mean * mean + 1e-5f);
    const float4 g0 = *(const float4*)&g[col];
    const float4 g1 = *(const float4*)&g[col + 4];
    const float4 b0 = *(const float4*)&b[col];
    const float4 b1 = *(const float4*)&b[col + 4];
    float4 o0, o1;
    o0.x = (v[0] - mean) * inv * g0.x + b0.x;
    o0.y = (v[1] - mean) * inv * g0.y + b0.y;
    o0.z = (v[2] - mean) * inv * g0.z + b0.z;
    o0.w = (v[3] - mean) * inv * g0.w + b0.w;
    o1.x = (v[4] - mean) * inv * g1.x + b1.x;
    o1.y = (v[5] - mean) * inv * g1.y + b1.y;
    o1.z = (v[6] - mean) * inv * g1.z + b1.z;
    o1.w = (v[7] - mean) * inv * g1.w + b1.w;
    *(float4*)&lnout[base]     = o0;
    *(float4*)&lnout[base + 4] = o1;
  }
}

// one wave per row of 512 (standalone LN, used once for layer-0 ln1)
__global__ __launch_bounds__(64) void ln_kernel(
    const float* __restrict__ x, const float* __restrict__ g,
    const float* __restrict__ b, float* __restrict__ out)
{
  const int row = blockIdx.x;
  const int lane = threadIdx.x;
  const float* xr = x + (size_t)row * NDIM;
  const float4 v0 = *(const float4*)&xr[lane * 8];
  const float4 v1 = *(const float4*)&xr[lane * 8 + 4];
  float s  = v0.x + v0.y + v0.z + v0.w + v1.x + v1.y + v1.z + v1.w;
  float sq = v0.x*v0.x + v0.y*v0.y + v0.z*v0.z + v0.w*v0.w
           + v1.x*v1.x + v1.y*v1.y + v1.z*v1.z + v1.w*v1.w;
#pragma unroll
  for (int m = 1; m < 64; m <<= 1) {
    s  += __shfl_xor(s, m);
    sq += __shfl_xor(sq, m);
  }
  const float mean = s * (1.0f / NDIM);
  const float inv = 1.0f / sqrtf(sq * (1.0f / NDIM) - mean * mean + 1e-5f);
  const float4 g0 = *(const float4*)&g[lane * 8];
  const float4 g1 = *(const float4*)&g[lane * 8 + 4];
  const float4 b0 = *(const float4*)&b[lane * 8];
  const float4 b1 = *(const float4*)&b[lane * 8 + 4];
  float4 o0, o1;
  o0.x = (v0.x - mean) * inv * g0.x + b0.x;
  o0.y = (v0.y - mean) * inv * g0.y + b0.y;
  o0.z = (v0.z - mean) * inv * g0.z + b0.z;
  o0.w = (v0.w - mean) * inv * g0.w + b0.w;
  o1.x = (v1.x - mean) * inv * g1.x + b1.x;
  o1.y = (v1.y - mean) * inv * g1.y + b1.y;
  o1.z = (v1.z - mean) * inv * g1.z + b1.z;
  o1.w = (v1.w - mean) * inv * g1.w + b1.w;
  *(float4*)&out[(size_t)row * NDIM + lane * 8]     = o0;
  *(float4*)&out[(size_t)row * NDIM + lane * 8 + 4] = o1;
}

// one wave per (head, token). qkv: [512][1536], att: [512][512]
__global__ __launch_bounds__(256) void natten_kernel(
    const float* __restrict__ qkv, const float* __restrict__ rpb,
    float* __restrict__ att)
{
  __shared__ float s_q[4][64];
  __shared__ float s_w[4][128];
  const int wid = threadIdx.x >> 6;
  const int lane = threadIdx.x & 63;
  const int idx = blockIdx.x * 4 + wid;
  const int i = idx & (SEQ - 1);
  const int h = idx >> 9;

  int ni = i - (KWIN / 2);
  ni = ni < 0 ? 0 : ni;
  ni = ni > (SEQ - KWIN) ? (SEQ - KWIN) : ni;
  const int pb = (KWIN - 1) - (i - ni);

  s_q[wid][lane] = qkv[(size_t)i * QKVD + h * NDH + lane] * 0.125f;
  __syncthreads();

  const float* krow0 = qkv + (size_t)(ni + lane) * QKVD + NDIM + h * NDH;
  float acc0 = 0.0f;
#pragma unroll
  for (int d = 0; d < NDH; d += 4) {
    const float4 q4 = *(const float4*)&s_q[wid][d];
    const float4 k4 = *(const float4*)&krow0[d];
    acc0 += q4.x*k4.x + q4.y*k4.y + q4.z*k4.z + q4.w*k4.w;
  }
  float l0 = acc0 + rpb[h * (2 * KWIN - 1) + pb + lane];
  float l1 = -1e30f;
  if (lane < KWIN - 64) {
    const float* krow1 = krow0 + 64 * QKVD;
    float acc1 = 0.0f;
#pragma unroll
    for (int d = 0; d < NDH; d += 4) {
      const float4 q4 = *(const float4*)&s_q[wid][d];
      const float4 k4 = *(const float4*)&krow1[d];
      acc1 += q4.x*k4.x + q4.y*k4.y + q4.z*k4.z + q4.w*k4.w;
    }
    l1 = acc1 + rpb[h * (2 * KWIN - 1) + pb + lane + 64];
  }

  float mx = fmaxf(l0, l1);
#pragma unroll
  for (int s = 1; s < 64; s <<= 1) mx = fmaxf(mx, __shfl_xor(mx, s));
  const float e0 = expf(l0 - mx);
  const float e1 = (lane < KWIN - 64) ? expf(l1 - mx) : 0.0f;
  float ssum = e0 + e1;
#pragma unroll
  for (int s = 1; s < 64; s <<= 1) ssum += __shfl_xor(ssum, s);
  const float rs = 1.0f / ssum;
  s_w[wid][lane] = e0 * rs;
  s_w[wid][64 + lane] = (lane < KWIN - 64) ? e1 * rs : 0.0f;
  __syncthreads();

  const float* vcol = qkv + (size_t)ni * QKVD + 2 * NDIM + h * NDH + lane;
  float o = 0.0f;
#pragma unroll 4
  for (int k = 0; k < KWIN; ++k)
    o = fmaf(s_w[wid][k], vcol[(size_t)k * QKVD], o);
  att[(size_t)i * NDIM + h * NDH + lane] = o;
}

// y[t*32+p] = tanh(b[p] + sum_d h[t][d] * W[p][d])
__global__ __launch_bounds__(256) void out_proj_kernel(
    const float* __restrict__ h, const float* __restrict__ W,
    const float* __restrict__ b, float* __restrict__ y)
{
  const int idx = blockIdx.x * 256 + threadIdx.x;
  const int t = idx >> 5;
  const int p = idx & 31;
  const float* hr = h + (size_t)t * NDIM;
  const float* wr = W + (size_t)p * NDIM;
  float acc = 0.0f;
#pragma unroll 4
  for (int d = 0; d < NDIM; d += 4) {
    const float4 a = *(const float4*)&hr[d];
    const float4 w = *(const float4*)&wr[d];
    acc += a.x*w.x + a.y*w.y + a.z*w.z + a.w*w.w;
  }
  y[idx] = tanhf(acc + b[p]);
}

extern "C" void kernel_launch(void* const* d_in, const int* in_sizes, int n_in,
                              void* d_out, int out_size, void* d_ws, size_t ws_size,
                              hipStream_t stream)
{
  const float* x      = (const float*)d_in[0];
  const float* in_w   = (const float*)d_in[1];
  const float* in_b   = (const float*)d_in[2];
  const float* ln1_g  = (const float*)d_in[3];
  const float* ln1_b  = (const float*)d_in[4];
  const float* qkv_w  = (const float*)d_in[5];
  const float* qkv_b  = (const float*)d_in[6];
  const float* rpb    = (const float*)d_in[7];
  const float* proj_w = (const float*)d_in[8];
  const float* proj_b = (const float*)d_in[9];
  const float* ln2_g  = (const float*)d_in[10];
  const float* ln2_b  = (const float*)d_in[11];
  const float* ff1_w  = (const float*)d_in[12];
  const float* ff1_b  = (const float*)d_in[13];
  const float* ff2_w  = (const float*)d_in[14];
  const float* ff2_b  = (const float*)d_in[15];
  const float* out_w  = (const float*)d_in[16];
  const float* out_b  = (const float*)d_in[17];
  float* y = (float*)d_out;

  float* ws  = (float*)d_ws;
  float* h   = ws;              // 512*512
  float* lnb = ws + 262144;     // 512*512
  float* qkv = ws + 524288;     // 512*1536
  float* att = ws + 1310720;    // 512*512
  float* z1  = ws + 1572864;    // 512*2048
  float* tmp = ws + 2621440;    // 4*512*512 split-K partials

  const dim3 blk(256);

  // patch embed (fp32, tiny): h = x(512x32) @ in_w^T + in_b
  gemm_nt<EP_BIAS><<<dim3(NDIM / 64, SEQ / 64, 1), blk, 0, stream>>>(
      x, in_w, in_b, h, SEQ, NDIM, NPATCH);
  // layer-0 ln1
  ln_kernel<<<dim3(SEQ), dim3(64), 0, stream>>>(h, ln1_g, ln1_b, lnb);

  for (int l = 0; l < NLAYERS; ++l) {
    // qkv = lnb @ qkv_w^T + qkv_b
    gemm_bf16<EP_BIAS><<<dim3(QKVD / 64, SEQ / 64, 1), blk, 0, stream>>>(
        lnb, qkv_w + (size_t)l * QKVD * NDIM, qkv_b + l * QKVD, qkv,
        SEQ, QKVD, NDIM);
    natten_kernel<<<dim3(NHEADS * SEQ / 4), blk, 0, stream>>>(
        qkv, rpb + (size_t)l * NHEADS * (2 * KWIN - 1), att);
    // proj partials (split-K=4)
    gemm_bf16<EP_NONE><<<dim3(NDIM / 64, SEQ / 64, 4), blk, 0, stream>>>(
        att, proj_w + (size_t)l * NDIM * NDIM, nullptr, tmp, SEQ, NDIM, NDIM);
    // h += proj + bias; lnb = ln2(h)
    reduce_ln<true><<<dim3(SEQ), dim3(64), 0, stream>>>(
        tmp, proj_b + l * NDIM, h, ln2_g + l * NDIM, ln2_b + l * NDIM, lnb);
    // z1 = gelu(lnb @ ff1_w^T + ff1_b)
    gemm_bf16<EP_BIAS_GELU><<<dim3(FFD / 64, SEQ / 64, 1), blk, 0, stream>>>(
        lnb, ff1_w + (size_t)l * FFD * NDIM, ff1_b + l * FFD, z1,
        SEQ, FFD, NDIM);
    // ff2 partials (split-K=4)
    gemm_bf16<EP_NONE><<<dim3(NDIM / 64, SEQ / 64, 4), blk, 0, stream>>>(
        z1, ff2_w + (size_t)l * NDIM * FFD, nullptr, tmp, SEQ, NDIM, FFD);
    // h += ff2 + bias; lnb = ln1_{l+1}(h) (skip LN after the last layer)
    if (l + 1 < NLAYERS) {
      reduce_ln<true><<<dim3(SEQ), dim3(64), 0, stream>>>(
          tmp, ff2_b + l * NDIM, h,
          ln1_g + (l + 1) * NDIM, ln1_b + (l + 1) * NDIM, lnb);
    } else {
      reduce_ln<false><<<dim3(SEQ), dim3(64), 0, stream>>>(
          tmp, ff2_b + l * NDIM, h, nullptr, nullptr, nullptr);
    }
  }

  out_proj_kernel<<<dim3(SEQ * NPATCH / 256), blk, 0, stream>>>(
      h, out_w, out_b, y);
}